// Round 12
// baseline (39.814 us; speedup 1.0000x reference)
//
#include <hip/hip_runtime.h>
#include <math.h>

// PointPillarFeatureNet, 3 dispatches, no atomics, no memset. (R9 base;
// single change: k_stats cross-lane reduce = LDS matrix, not shfl butterfly.)
//  k_stats: 469 blocks x 64 pillars: per-pillar raw moments (quad-of-lanes)
//           -> rank-1 corrections (quad leaders) -> leaders write 54 partials
//           to LDS [64][57] (stride 57 -> bank step 25, conflict-free) ->
//           216-thread parallel reduce -> ws row [b*64+e]. Stores meta.
//  k_mid:   1 block x 1024 thr: 16-chain x 4-unroll ILP reduce of the nb rows
//           -> BN mean/var closed form -> 10 folded per-channel constants.
//  k_out:   (R9 verbatim) slot data wave-uniform -> scalar s_load_dwordx16;
//           separate-asm waitcnt + sched_barrier(0) (rule 18); slots 16-31
//           under a scalar branch on np. Zero LDS in main loop.
// ws layout (floats): [0 .. nb*64)   block partials (cols 54..63 junk)
//                     [foff..+640)   folded consts, SoA j*64+d, j<10
//                     [moff..+8P)    pillar meta (mx,my,mz,np_bits,cx,cy)

#define NSLOT 32
#define NCH 64

static constexpr float kVX = 0.16f, kVY = 0.16f;
static constexpr float kXOff = 0.08f;            // VX/2 + 0.0
static constexpr float kYOff = 0.08f - 39.68f;   // VY/2 - 39.68
static constexpr float kEps = 1e-3f;

typedef int sv16 __attribute__((ext_vector_type(16)));
typedef int sv8 __attribute__((ext_vector_type(8)));
union U16 { sv16 v; float f[16]; };
union U8  { sv8 v;  float f[8]; int i[8]; };

// Force a pointer into SGPRs (provably wave-uniform for the "s" constraint).
__device__ __forceinline__ const float* uptr(const float* p) {
    unsigned long long v = (unsigned long long)p;
    unsigned lo = __builtin_amdgcn_readfirstlane((unsigned)v);
    unsigned hi = __builtin_amdgcn_readfirstlane((unsigned)(v >> 32));
    return (const float*)(((unsigned long long)hi << 32) | lo);
}

__global__ __launch_bounds__(256) void k_stats(const float* __restrict__ in,
                                               const int* __restrict__ npts,
                                               const int* __restrict__ coords,
                                               float* __restrict__ part,
                                               float* __restrict__ meta, int P) {
    __shared__ float Rm[64][57];   // per-pillar 54 partials, padded stride 57
    __shared__ float s2[4][54];
    const int tid = threadIdx.x;
    const int lane = tid & 63;
    const int wv = tid >> 6;
    const int sub = lane & 3;
    const int pi = blockIdx.x * 64 + wv * 16 + (lane >> 2);
    const bool valid = pi < P;

    float T0 = 0.f, T1 = 0.f, T2 = 0.f;
    float S0 = 0.f, S1 = 0.f, S2 = 0.f, S3 = 0.f;
    float Q[10];
#pragma unroll
    for (int i = 0; i < 10; ++i) Q[i] = 0.f;
    float cx = 0.f, cy = 0.f, npf = 1.f;
    int np = 1;

    if (valid) {
        np = npts[pi];
        np = np < 1 ? 1 : (np > NSLOT ? NSLOT : np);
        npf = (float)np;
        const int4 cd = *reinterpret_cast<const int4*>(coords + (size_t)pi * 4);
        cx = (float)cd.w * kVX + kXOff;
        cy = (float)cd.z * kVY + kYOff;
        const float* bp = in + (size_t)pi * 128 + sub * 4;
#pragma unroll
        for (int k = 0; k < 8; ++k) {
            const float4 u = *reinterpret_cast<const float4*>(bp + k * 16);
            const int slot = sub + k * 4;
            T0 += u.x; T1 += u.y; T2 += u.z;
            const bool m = slot < np;
            const float ax = m ? u.x : 0.f, ay = m ? u.y : 0.f;
            const float az = m ? u.z : 0.f, aw = m ? u.w : 0.f;
            S0 += ax; S1 += ay; S2 += az; S3 += aw;
            Q[0] += ax * u.x; Q[1] += ax * u.y; Q[2] += ax * u.z; Q[3] += ax * u.w;
            Q[4] += ay * u.y; Q[5] += ay * u.z; Q[6] += ay * u.w;
            Q[7] += az * u.z; Q[8] += az * u.w;
            Q[9] += aw * u.w;
        }
    }

#define QUADR(v) { v += __shfl_xor(v, 1); v += __shfl_xor(v, 2); }
    QUADR(T0) QUADR(T1) QUADR(T2)
    QUADR(S0) QUADR(S1) QUADR(S2) QUADR(S3)
#pragma unroll
    for (int i = 0; i < 10; ++i) QUADR(Q[i])
#undef QUADR

    float acc[54];
#pragma unroll
    for (int i = 0; i < 54; ++i) acc[i] = 0.f;

    if (valid && sub == 0) {
        const float inv = 1.0f / npf;
        const float mx = T0 * inv, my = T1 * inv, mz = T2 * inv;
        *reinterpret_cast<float4*>(meta + (size_t)pi * 8) =
            make_float4(mx, my, mz, __int_as_float(np));
        *reinterpret_cast<float4*>(meta + (size_t)pi * 8 + 4) =
            make_float4(cx, cy, 0.f, 0.f);
        const float AS[9] = {S0, S1, S2, S3, S0, S1, S2, S0, S1};
        const float b9[9] = {0.f, 0.f, 0.f, 0.f, -mx, -my, -mz, -cx, -cy};
        const int r9[9] = {0, 1, 2, 3, 0, 1, 2, 0, 1};
        float Qm[4][4];
        Qm[0][0] = Q[0]; Qm[0][1] = Q[1]; Qm[0][2] = Q[2]; Qm[0][3] = Q[3];
        Qm[1][0] = Q[1]; Qm[1][1] = Q[4]; Qm[1][2] = Q[5]; Qm[1][3] = Q[6];
        Qm[2][0] = Q[2]; Qm[2][1] = Q[5]; Qm[2][2] = Q[7]; Qm[2][3] = Q[8];
        Qm[3][0] = Q[3]; Qm[3][1] = Q[6]; Qm[3][2] = Q[8]; Qm[3][3] = Q[9];
#pragma unroll
        for (int i = 0; i < 9; ++i) acc[i] = AS[i] + npf * b9[i];
        int k = 9;
#pragma unroll
        for (int i = 0; i < 9; ++i)
#pragma unroll
            for (int j = i; j < 9; ++j) {
                acc[k] = Qm[r9[i]][r9[j]] + AS[i] * b9[j] + b9[i] * AS[j]
                         + npf * b9[i] * b9[j];
                ++k;
            }
    }

    // leaders (sub==0; zeros for invalid pillars) write partials to LDS
    {
        const int q = wv * 16 + (lane >> 2);
        if (sub == 0) {
#pragma unroll
            for (int e = 0; e < 54; ++e) Rm[q][e] = acc[e];
        }
    }
    __syncthreads();
    // 216-thread parallel reduce: (g,e) sums rows g*16..g*16+15 of column e
    {
        const int e = tid & 63;
        const int g = tid >> 6;
        if (e < 54) {
            float v = 0.f;
#pragma unroll
            for (int r = 0; r < 16; ++r) v += Rm[g * 16 + r][e];
            s2[g][e] = v;
        }
    }
    __syncthreads();
    if (tid < 54) {
        part[(size_t)blockIdx.x * 64 + tid] =
            s2[0][tid] + s2[1][tid] + s2[2][tid] + s2[3][tid];
    }
}

// 1 block x 1024 threads: ILP reduce of nb rows + BN fold.
__global__ __launch_bounds__(1024) void k_mid(const float* __restrict__ part,
                                              const float* __restrict__ W,
                                              const float* __restrict__ gamma,
                                              const float* __restrict__ beta,
                                              float* __restrict__ fold,
                                              int nb, int P) {
    __shared__ float sred[16][64];
    __shared__ float ssum[64];
    const int tid = threadIdx.x;
    const int e = tid & 63;
    const int grp = tid >> 6;  // 16 chains per element
    float v0 = 0.f, v1 = 0.f, v2 = 0.f, v3 = 0.f;
    int i = grp;
    for (; i + 48 < nb; i += 64) {
        v0 += part[(size_t)i * 64 + e];
        v1 += part[(size_t)(i + 16) * 64 + e];
        v2 += part[(size_t)(i + 32) * 64 + e];
        v3 += part[(size_t)(i + 48) * 64 + e];
    }
    for (; i < nb; i += 16) v0 += part[(size_t)i * 64 + e];
    sred[grp][e] = (v0 + v1) + (v2 + v3);
    __syncthreads();
    if (tid < 64) {
        float v = 0.f;
#pragma unroll
        for (int g = 0; g < 16; ++g) v += sred[g][tid];
        ssum[tid] = v;  // cols 54..63 junk, never used below
    }
    __syncthreads();

    if (tid < 64) {
        const int d = tid;
        float Wc[9];
#pragma unroll
        for (int c = 0; c < 9; ++c) Wc[c] = W[c * NCH + d];
        const float invPN = 1.0f / ((float)P * (float)NSLOT);
        float mean = 0.f;
#pragma unroll
        for (int c = 0; c < 9; ++c) mean += ssum[c] * Wc[c];
        mean *= invPN;
        float e2 = 0.f;
        int k = 9;
#pragma unroll
        for (int i2 = 0; i2 < 9; ++i2)
#pragma unroll
            for (int j = i2; j < 9; ++j) {
                const float coef = (i2 == j) ? 1.f : 2.f;
                e2 += coef * ssum[k] * Wc[i2] * Wc[j];
                ++k;
            }
        e2 *= invPN;
        const float var = e2 - mean * mean;
        const float s = gamma[d] * rsqrtf(var + kEps);
        const float t = beta[d] - mean * s;
        fold[0 * 64 + d] = s * (Wc[0] + Wc[4] + Wc[7]);  // V0
        fold[1 * 64 + d] = s * (Wc[1] + Wc[5] + Wc[8]);  // V1
        fold[2 * 64 + d] = s * (Wc[2] + Wc[6]);          // V2
        fold[3 * 64 + d] = s * Wc[3];                    // V3
        fold[4 * 64 + d] = s * Wc[4];
        fold[5 * 64 + d] = s * Wc[5];
        fold[6 * 64 + d] = s * Wc[6];
        fold[7 * 64 + d] = s * Wc[7];
        fold[8 * 64 + d] = s * Wc[8];
        fold[9 * 64 + d] = t;
    }
}

__global__ __launch_bounds__(256) void k_out(const float* __restrict__ in,
                                             const float* __restrict__ fold,
                                             const float* __restrict__ meta,
                                             float* __restrict__ out, int P) {
    const int tid = threadIdx.x;
    const int lane = tid & 63;
    const int wv = tid >> 6;
    const int gwave = blockIdx.x * 4 + wv;
    const int nwave = gridDim.x * 4;

    float F[10];
#pragma unroll
    for (int j = 0; j < 10; ++j) F[j] = fold[j * 64 + lane];
    const float V0 = F[0], V1 = F[1], V2 = F[2], V3 = F[3];
    const float sW4 = F[4], sW5 = F[5], sW6 = F[6], sW7 = F[7], sW8 = F[8];
    const float t = F[9];

    for (int p = gwave; p < P; p += nwave) {
        const float* up = uptr(in + (size_t)p * 128);
        const float* mp = uptr(meta + (size_t)p * 8);
        U8 m; U16 g0, g1, g2, g3;
        asm volatile(
            "s_load_dwordx8 %0, %2, 0x0\n\t"
            "s_load_dwordx16 %1, %3, 0x0"
            : "=s"(m.v), "=s"(g0.v) : "s"(mp), "s"(up));
        asm volatile(
            "s_load_dwordx16 %0, %2, 0x40\n\t"
            "s_load_dwordx16 %1, %2, 0x80"
            : "=s"(g1.v), "=s"(g2.v) : "s"(up));
        asm volatile(
            "s_load_dwordx16 %0, %1, 0xc0"
            : "=s"(g3.v) : "s"(up));
        // rule 18: waitcnt in its own asm + sched_barrier so the compiler
        // cannot hoist the SGPR-consuming FMAs above the wait.
        asm volatile("s_waitcnt lgkmcnt(0)" ::: "memory");
        __builtin_amdgcn_sched_barrier(0);

        const int np = m.i[3];  // SGPR -> scalar branches below
        const float c0 = t - fmaf(m.f[0], sW4, fmaf(m.f[1], sW5,
                             fmaf(m.f[2], sW6, fmaf(m.f[4], sW7,
                                  m.f[5] * sW8))));
        // np <= 31 always -> masked slots contribute t; seed with t
        float y0 = t, y1 = t, y2 = t, y3 = t;
#define SLOT4(G, B) { \
        const float z0 = fmaf(G.f[0], V0, fmaf(G.f[1], V1, \
                           fmaf(G.f[2], V2, fmaf(G.f[3], V3, c0)))); \
        const float z1 = fmaf(G.f[4], V0, fmaf(G.f[5], V1, \
                           fmaf(G.f[6], V2, fmaf(G.f[7], V3, c0)))); \
        const float z2 = fmaf(G.f[8], V0, fmaf(G.f[9], V1, \
                           fmaf(G.f[10], V2, fmaf(G.f[11], V3, c0)))); \
        const float z3 = fmaf(G.f[12], V0, fmaf(G.f[13], V1, \
                           fmaf(G.f[14], V2, fmaf(G.f[15], V3, c0)))); \
        y0 = fmaxf(y0, ((B) + 0 < np) ? z0 : t); \
        y1 = fmaxf(y1, ((B) + 1 < np) ? z1 : t); \
        y2 = fmaxf(y2, ((B) + 2 < np) ? z2 : t); \
        y3 = fmaxf(y3, ((B) + 3 < np) ? z3 : t); }

        SLOT4(g0, 0)
        SLOT4(g1, 4)
        if (np > 8) {   // scalar branch (np in SGPR)
            SLOT4(g2, 8)
            SLOT4(g3, 12)
        }
        if (np > 16) {  // scalar branch; ~48% of pillars
            U16 h0, h1, h2, h3;
            asm volatile(
                "s_load_dwordx16 %0, %2, 0x100\n\t"
                "s_load_dwordx16 %1, %2, 0x140"
                : "=s"(h0.v), "=s"(h1.v) : "s"(up));
            asm volatile(
                "s_load_dwordx16 %0, %2, 0x180\n\t"
                "s_load_dwordx16 %1, %2, 0x1c0"
                : "=s"(h2.v), "=s"(h3.v) : "s"(up));
            asm volatile("s_waitcnt lgkmcnt(0)" ::: "memory");
            __builtin_amdgcn_sched_barrier(0);
            SLOT4(h0, 16)
            SLOT4(h1, 20)
            SLOT4(h2, 24)
            SLOT4(h3, 28)
        }
#undef SLOT4
        out[(size_t)p * NCH + lane] =
            fmaxf(fmaxf(fmaxf(y0, y1), fmaxf(y2, y3)), 0.f);
    }
}

extern "C" void kernel_launch(void* const* d_in, const int* in_sizes, int n_in,
                              void* d_out, int out_size, void* d_ws, size_t ws_size,
                              hipStream_t stream) {
    const float* in = (const float*)d_in[0];
    const int* npts = (const int*)d_in[1];
    const int* coords = (const int*)d_in[2];
    const float* W = (const float*)d_in[3];
    const float* gamma = (const float*)d_in[4];
    const float* beta = (const float*)d_in[5];
    float* out = (float*)d_out;
    float* ws = (float*)d_ws;
    const int P = in_sizes[1];  // num_points has P elements

    const int nb = (P + 63) / 64;                 // 469 for P=30000
    const size_t foff = (size_t)nb * 64;          // folded consts offset
    const size_t moff = (foff + 640 + 63) & ~(size_t)63;  // meta offset
    float* part = ws;
    float* fold = ws + foff;
    float* meta = ws + moff;   // ws_size (observed 268 MB) >> 17 MB needed

    k_stats<<<nb, 256, 0, stream>>>(in, npts, coords, part, meta, P);
    k_mid<<<1, 1024, 0, stream>>>(part, W, gamma, beta, fold, nb, P);
    k_out<<<2048, 256, 0, stream>>>(in, fold, meta, out, P);
}

// Round 13
// 30.766 us; speedup vs baseline: 1.2941x; 1.2941x over previous
//
#include <hip/hip_runtime.h>
#include <math.h>

// PointPillarFeatureNet, 3 dispatches, no atomics, no memset. (R9 verbatim —
// best measured 31.3us; resubmitted as a session-variance re-anchor after
// R11/R12 regressions coincided with ~8% slower poison-fill BW.)
//  k_stats: 469 blocks x 64 pillars: per-pillar raw moments (quad-of-lanes)
//           -> rank-1 corrections -> block partial of the 54 augmented-moment
//           sums -> ws row [b*64+e] (non-atomic). Stores per-pillar meta.
//  k_mid:   1 block x 1024 thr: 16-chain x 4-unroll ILP reduce of the nb rows
//           -> BN mean/var closed form -> 10 folded per-channel constants.
//  k_out:   slot data is wave-uniform -> scalar loads via readfirstlane'd
//           pointers (s_load_dwordx16 = 4 slots). Waits are separate asm +
//           sched_barrier(0) (rule 18). Slots 16-31 under a SCALAR branch.
//           Zero LDS. 4 fma (1 SGPR src each) + sel + max per slot.
// ws layout (floats): [0 .. nb*64)          block partials (cols 54..63 junk)
//                     [foff .. foff+640)    folded consts, SoA j*64+d, j<10
//                     [moff .. moff+8P)     pillar meta (mx,my,mz,np_bits,cx,cy)

#define NSLOT 32
#define NCH 64

static constexpr float kVX = 0.16f, kVY = 0.16f;
static constexpr float kXOff = 0.08f;            // VX/2 + 0.0
static constexpr float kYOff = 0.08f - 39.68f;   // VY/2 - 39.68
static constexpr float kEps = 1e-3f;
static constexpr float kNegInf = -3.402823466e38f;

typedef int sv16 __attribute__((ext_vector_type(16)));
typedef int sv8 __attribute__((ext_vector_type(8)));
union U16 { sv16 v; float f[16]; };
union U8  { sv8 v;  float f[8]; int i[8]; };

// Force a pointer into SGPRs (provably wave-uniform for the "s" constraint).
__device__ __forceinline__ const float* uptr(const float* p) {
    unsigned long long v = (unsigned long long)p;
    unsigned lo = __builtin_amdgcn_readfirstlane((unsigned)v);
    unsigned hi = __builtin_amdgcn_readfirstlane((unsigned)(v >> 32));
    return (const float*)(((unsigned long long)hi << 32) | lo);
}

__global__ __launch_bounds__(256) void k_stats(const float* __restrict__ in,
                                               const int* __restrict__ npts,
                                               const int* __restrict__ coords,
                                               float* __restrict__ part,
                                               float* __restrict__ meta, int P) {
    const int tid = threadIdx.x;
    const int lane = tid & 63;
    const int wv = tid >> 6;
    const int sub = lane & 3;
    const int pi = blockIdx.x * 64 + wv * 16 + (lane >> 2);
    const bool valid = pi < P;

    float T0 = 0.f, T1 = 0.f, T2 = 0.f;
    float S0 = 0.f, S1 = 0.f, S2 = 0.f, S3 = 0.f;
    float Q[10];
#pragma unroll
    for (int i = 0; i < 10; ++i) Q[i] = 0.f;
    float cx = 0.f, cy = 0.f, npf = 1.f;
    int np = 1;

    if (valid) {
        np = npts[pi];
        np = np < 1 ? 1 : (np > NSLOT ? NSLOT : np);
        npf = (float)np;
        const int4 cd = *reinterpret_cast<const int4*>(coords + (size_t)pi * 4);
        cx = (float)cd.w * kVX + kXOff;
        cy = (float)cd.z * kVY + kYOff;
        const float* bp = in + (size_t)pi * 128 + sub * 4;
#pragma unroll
        for (int k = 0; k < 8; ++k) {
            const float4 u = *reinterpret_cast<const float4*>(bp + k * 16);
            const int slot = sub + k * 4;
            T0 += u.x; T1 += u.y; T2 += u.z;
            const bool m = slot < np;
            const float ax = m ? u.x : 0.f, ay = m ? u.y : 0.f;
            const float az = m ? u.z : 0.f, aw = m ? u.w : 0.f;
            S0 += ax; S1 += ay; S2 += az; S3 += aw;
            Q[0] += ax * u.x; Q[1] += ax * u.y; Q[2] += ax * u.z; Q[3] += ax * u.w;
            Q[4] += ay * u.y; Q[5] += ay * u.z; Q[6] += ay * u.w;
            Q[7] += az * u.z; Q[8] += az * u.w;
            Q[9] += aw * u.w;
        }
    }

#define QUADR(v) { v += __shfl_xor(v, 1); v += __shfl_xor(v, 2); }
    QUADR(T0) QUADR(T1) QUADR(T2)
    QUADR(S0) QUADR(S1) QUADR(S2) QUADR(S3)
#pragma unroll
    for (int i = 0; i < 10; ++i) QUADR(Q[i])
#undef QUADR

    float acc[54];
#pragma unroll
    for (int i = 0; i < 54; ++i) acc[i] = 0.f;

    if (valid && sub == 0) {
        const float inv = 1.0f / npf;
        const float mx = T0 * inv, my = T1 * inv, mz = T2 * inv;
        *reinterpret_cast<float4*>(meta + (size_t)pi * 8) =
            make_float4(mx, my, mz, __int_as_float(np));
        *reinterpret_cast<float4*>(meta + (size_t)pi * 8 + 4) =
            make_float4(cx, cy, 0.f, 0.f);
        const float AS[9] = {S0, S1, S2, S3, S0, S1, S2, S0, S1};
        const float b9[9] = {0.f, 0.f, 0.f, 0.f, -mx, -my, -mz, -cx, -cy};
        const int r9[9] = {0, 1, 2, 3, 0, 1, 2, 0, 1};
        float Qm[4][4];
        Qm[0][0] = Q[0]; Qm[0][1] = Q[1]; Qm[0][2] = Q[2]; Qm[0][3] = Q[3];
        Qm[1][0] = Q[1]; Qm[1][1] = Q[4]; Qm[1][2] = Q[5]; Qm[1][3] = Q[6];
        Qm[2][0] = Q[2]; Qm[2][1] = Q[5]; Qm[2][2] = Q[7]; Qm[2][3] = Q[8];
        Qm[3][0] = Q[3]; Qm[3][1] = Q[6]; Qm[3][2] = Q[8]; Qm[3][3] = Q[9];
#pragma unroll
        for (int i = 0; i < 9; ++i) acc[i] = AS[i] + npf * b9[i];
        int k = 9;
#pragma unroll
        for (int i = 0; i < 9; ++i)
#pragma unroll
            for (int j = i; j < 9; ++j) {
                acc[k] = Qm[r9[i]][r9[j]] + AS[i] * b9[j] + b9[i] * AS[j]
                         + npf * b9[i] * b9[j];
                ++k;
            }
    }

    // reduce across the 16 quad-leader lanes (others hold zeros)
#pragma unroll
    for (int i = 0; i < 54; ++i) {
        acc[i] += __shfl_xor(acc[i], 4);
        acc[i] += __shfl_xor(acc[i], 8);
        acc[i] += __shfl_xor(acc[i], 16);
        acc[i] += __shfl_xor(acc[i], 32);
    }

    __shared__ float red[4][54];
    if (lane == 0) {
#pragma unroll
        for (int i = 0; i < 54; ++i) red[wv][i] = acc[i];
    }
    __syncthreads();
    if (tid < 54) {
        part[(size_t)blockIdx.x * 64 + tid] =
            red[0][tid] + red[1][tid] + red[2][tid] + red[3][tid];
    }
}

// 1 block x 1024 threads: ILP reduce of nb rows + BN fold.
__global__ __launch_bounds__(1024) void k_mid(const float* __restrict__ part,
                                              const float* __restrict__ W,
                                              const float* __restrict__ gamma,
                                              const float* __restrict__ beta,
                                              float* __restrict__ fold,
                                              int nb, int P) {
    __shared__ float sred[16][64];
    __shared__ float ssum[64];
    const int tid = threadIdx.x;
    const int e = tid & 63;
    const int grp = tid >> 6;  // 16 chains per element
    float v0 = 0.f, v1 = 0.f, v2 = 0.f, v3 = 0.f;
    int i = grp;
    for (; i + 48 < nb; i += 64) {
        v0 += part[(size_t)i * 64 + e];
        v1 += part[(size_t)(i + 16) * 64 + e];
        v2 += part[(size_t)(i + 32) * 64 + e];
        v3 += part[(size_t)(i + 48) * 64 + e];
    }
    for (; i < nb; i += 16) v0 += part[(size_t)i * 64 + e];
    sred[grp][e] = (v0 + v1) + (v2 + v3);
    __syncthreads();
    if (tid < 64) {
        float v = 0.f;
#pragma unroll
        for (int g = 0; g < 16; ++g) v += sred[g][tid];
        ssum[tid] = v;  // cols 54..63 junk, never used below
    }
    __syncthreads();

    if (tid < 64) {
        const int d = tid;
        float Wc[9];
#pragma unroll
        for (int c = 0; c < 9; ++c) Wc[c] = W[c * NCH + d];
        const float invPN = 1.0f / ((float)P * (float)NSLOT);
        float mean = 0.f;
#pragma unroll
        for (int c = 0; c < 9; ++c) mean += ssum[c] * Wc[c];
        mean *= invPN;
        float e2 = 0.f;
        int k = 9;
#pragma unroll
        for (int i2 = 0; i2 < 9; ++i2)
#pragma unroll
            for (int j = i2; j < 9; ++j) {
                const float coef = (i2 == j) ? 1.f : 2.f;
                e2 += coef * ssum[k] * Wc[i2] * Wc[j];
                ++k;
            }
        e2 *= invPN;
        const float var = e2 - mean * mean;
        const float s = gamma[d] * rsqrtf(var + kEps);
        const float t = beta[d] - mean * s;
        fold[0 * 64 + d] = s * (Wc[0] + Wc[4] + Wc[7]);  // V0
        fold[1 * 64 + d] = s * (Wc[1] + Wc[5] + Wc[8]);  // V1
        fold[2 * 64 + d] = s * (Wc[2] + Wc[6]);          // V2
        fold[3 * 64 + d] = s * Wc[3];                    // V3
        fold[4 * 64 + d] = s * Wc[4];
        fold[5 * 64 + d] = s * Wc[5];
        fold[6 * 64 + d] = s * Wc[6];
        fold[7 * 64 + d] = s * Wc[7];
        fold[8 * 64 + d] = s * Wc[8];
        fold[9 * 64 + d] = t;
    }
}

__global__ __launch_bounds__(256) void k_out(const float* __restrict__ in,
                                             const float* __restrict__ fold,
                                             const float* __restrict__ meta,
                                             float* __restrict__ out, int P) {
    const int tid = threadIdx.x;
    const int lane = tid & 63;
    const int wv = tid >> 6;
    const int gwave = blockIdx.x * 4 + wv;
    const int nwave = gridDim.x * 4;

    float F[10];
#pragma unroll
    for (int j = 0; j < 10; ++j) F[j] = fold[j * 64 + lane];
    const float V0 = F[0], V1 = F[1], V2 = F[2], V3 = F[3];
    const float sW4 = F[4], sW5 = F[5], sW6 = F[6], sW7 = F[7], sW8 = F[8];
    const float t = F[9];

    for (int p = gwave; p < P; p += nwave) {
        const float* up = uptr(in + (size_t)p * 128);
        const float* mp = uptr(meta + (size_t)p * 8);
        U8 m; U16 g0, g1, g2, g3;
        asm volatile(
            "s_load_dwordx8 %0, %2, 0x0\n\t"
            "s_load_dwordx16 %1, %3, 0x0"
            : "=s"(m.v), "=s"(g0.v) : "s"(mp), "s"(up));
        asm volatile(
            "s_load_dwordx16 %0, %2, 0x40\n\t"
            "s_load_dwordx16 %1, %2, 0x80"
            : "=s"(g1.v), "=s"(g2.v) : "s"(up));
        asm volatile(
            "s_load_dwordx16 %0, %1, 0xc0"
            : "=s"(g3.v) : "s"(up));
        // rule 18: waitcnt in its own asm + sched_barrier so the compiler
        // cannot hoist the SGPR-consuming FMAs above the wait.
        asm volatile("s_waitcnt lgkmcnt(0)" ::: "memory");
        __builtin_amdgcn_sched_barrier(0);

        const int np = m.i[3];  // SGPR -> scalar branches below
        const float c0 = t - fmaf(m.f[0], sW4, fmaf(m.f[1], sW5,
                             fmaf(m.f[2], sW6, fmaf(m.f[4], sW7,
                                  m.f[5] * sW8))));
        // np <= 31 always -> masked slots contribute t; seed with t
        float y0 = t, y1 = t, y2 = t, y3 = t;
#define SLOT4(G, B) { \
        const float z0 = fmaf(G.f[0], V0, fmaf(G.f[1], V1, \
                           fmaf(G.f[2], V2, fmaf(G.f[3], V3, c0)))); \
        const float z1 = fmaf(G.f[4], V0, fmaf(G.f[5], V1, \
                           fmaf(G.f[6], V2, fmaf(G.f[7], V3, c0)))); \
        const float z2 = fmaf(G.f[8], V0, fmaf(G.f[9], V1, \
                           fmaf(G.f[10], V2, fmaf(G.f[11], V3, c0)))); \
        const float z3 = fmaf(G.f[12], V0, fmaf(G.f[13], V1, \
                           fmaf(G.f[14], V2, fmaf(G.f[15], V3, c0)))); \
        y0 = fmaxf(y0, ((B) + 0 < np) ? z0 : t); \
        y1 = fmaxf(y1, ((B) + 1 < np) ? z1 : t); \
        y2 = fmaxf(y2, ((B) + 2 < np) ? z2 : t); \
        y3 = fmaxf(y3, ((B) + 3 < np) ? z3 : t); }

        SLOT4(g0, 0)
        SLOT4(g1, 4)
        if (np > 8) {   // scalar branch (np in SGPR)
            SLOT4(g2, 8)
            SLOT4(g3, 12)
        }
        if (np > 16) {  // scalar branch; ~48% of pillars
            U16 h0, h1, h2, h3;
            asm volatile(
                "s_load_dwordx16 %0, %2, 0x100\n\t"
                "s_load_dwordx16 %1, %2, 0x140"
                : "=s"(h0.v), "=s"(h1.v) : "s"(up));
            asm volatile(
                "s_load_dwordx16 %0, %2, 0x180\n\t"
                "s_load_dwordx16 %1, %2, 0x1c0"
                : "=s"(h2.v), "=s"(h3.v) : "s"(up));
            asm volatile("s_waitcnt lgkmcnt(0)" ::: "memory");
            __builtin_amdgcn_sched_barrier(0);
            SLOT4(h0, 16)
            SLOT4(h1, 20)
            SLOT4(h2, 24)
            SLOT4(h3, 28)
        }
#undef SLOT4
        out[(size_t)p * NCH + lane] =
            fmaxf(fmaxf(fmaxf(y0, y1), fmaxf(y2, y3)), 0.f);
    }
}

extern "C" void kernel_launch(void* const* d_in, const int* in_sizes, int n_in,
                              void* d_out, int out_size, void* d_ws, size_t ws_size,
                              hipStream_t stream) {
    const float* in = (const float*)d_in[0];
    const int* npts = (const int*)d_in[1];
    const int* coords = (const int*)d_in[2];
    const float* W = (const float*)d_in[3];
    const float* gamma = (const float*)d_in[4];
    const float* beta = (const float*)d_in[5];
    float* out = (float*)d_out;
    float* ws = (float*)d_ws;
    const int P = in_sizes[1];  // num_points has P elements

    const int nb = (P + 63) / 64;                 // 469 for P=30000
    const size_t foff = (size_t)nb * 64;          // folded consts offset
    const size_t moff = (foff + 640 + 63) & ~(size_t)63;  // meta offset
    float* part = ws;
    float* fold = ws + foff;
    float* meta = ws + moff;   // ws_size (observed 268 MB) >> 17 MB needed

    k_stats<<<nb, 256, 0, stream>>>(in, npts, coords, part, meta, P);
    k_mid<<<1, 1024, 0, stream>>>(part, W, gamma, beta, fold, nb, P);
    k_out<<<2048, 256, 0, stream>>>(in, fold, meta, out, P);
}

// Round 14
// 30.218 us; speedup vs baseline: 1.3175x; 1.0181x over previous
//
#include <hip/hip_runtime.h>
#include <math.h>

// PointPillarFeatureNet, 3 dispatches, no atomics, no memset. (R13 base;
// single change: k_out grid 2048 -> 4096 for shorter serial-SMEM tails.)
//  k_stats: 469 blocks x 64 pillars: per-pillar raw moments (quad-of-lanes)
//           -> rank-1 corrections -> block partial of the 54 augmented-moment
//           sums -> ws row [b*64+e] (non-atomic). Stores per-pillar meta.
//           (Cross-lane reduce = shfl butterfly; LDS-matrix variant measured
//            +8us in R11/R12 — do not revisit.)
//  k_mid:   1 block x 1024 thr: 16-chain x 4-unroll ILP reduce of the nb rows
//           -> BN mean/var closed form -> 10 folded per-channel constants.
//  k_out:   slot data is wave-uniform -> scalar loads via readfirstlane'd
//           pointers (s_load_dwordx16 = 4 slots). Waits are separate asm +
//           sched_barrier(0) (rule 18). Slots 16-31 under a SCALAR branch.
//           Zero LDS. 4 fma (1 SGPR src each) + sel + max per slot.
// ws layout (floats): [0 .. nb*64)          block partials (cols 54..63 junk)
//                     [foff .. foff+640)    folded consts, SoA j*64+d, j<10
//                     [moff .. moff+8P)     pillar meta (mx,my,mz,np_bits,cx,cy)

#define NSLOT 32
#define NCH 64

static constexpr float kVX = 0.16f, kVY = 0.16f;
static constexpr float kXOff = 0.08f;            // VX/2 + 0.0
static constexpr float kYOff = 0.08f - 39.68f;   // VY/2 - 39.68
static constexpr float kEps = 1e-3f;

typedef int sv16 __attribute__((ext_vector_type(16)));
typedef int sv8 __attribute__((ext_vector_type(8)));
union U16 { sv16 v; float f[16]; };
union U8  { sv8 v;  float f[8]; int i[8]; };

// Force a pointer into SGPRs (provably wave-uniform for the "s" constraint).
__device__ __forceinline__ const float* uptr(const float* p) {
    unsigned long long v = (unsigned long long)p;
    unsigned lo = __builtin_amdgcn_readfirstlane((unsigned)v);
    unsigned hi = __builtin_amdgcn_readfirstlane((unsigned)(v >> 32));
    return (const float*)(((unsigned long long)hi << 32) | lo);
}

__global__ __launch_bounds__(256) void k_stats(const float* __restrict__ in,
                                               const int* __restrict__ npts,
                                               const int* __restrict__ coords,
                                               float* __restrict__ part,
                                               float* __restrict__ meta, int P) {
    const int tid = threadIdx.x;
    const int lane = tid & 63;
    const int wv = tid >> 6;
    const int sub = lane & 3;
    const int pi = blockIdx.x * 64 + wv * 16 + (lane >> 2);
    const bool valid = pi < P;

    float T0 = 0.f, T1 = 0.f, T2 = 0.f;
    float S0 = 0.f, S1 = 0.f, S2 = 0.f, S3 = 0.f;
    float Q[10];
#pragma unroll
    for (int i = 0; i < 10; ++i) Q[i] = 0.f;
    float cx = 0.f, cy = 0.f, npf = 1.f;
    int np = 1;

    if (valid) {
        np = npts[pi];
        np = np < 1 ? 1 : (np > NSLOT ? NSLOT : np);
        npf = (float)np;
        const int4 cd = *reinterpret_cast<const int4*>(coords + (size_t)pi * 4);
        cx = (float)cd.w * kVX + kXOff;
        cy = (float)cd.z * kVY + kYOff;
        const float* bp = in + (size_t)pi * 128 + sub * 4;
#pragma unroll
        for (int k = 0; k < 8; ++k) {
            const float4 u = *reinterpret_cast<const float4*>(bp + k * 16);
            const int slot = sub + k * 4;
            T0 += u.x; T1 += u.y; T2 += u.z;
            const bool m = slot < np;
            const float ax = m ? u.x : 0.f, ay = m ? u.y : 0.f;
            const float az = m ? u.z : 0.f, aw = m ? u.w : 0.f;
            S0 += ax; S1 += ay; S2 += az; S3 += aw;
            Q[0] += ax * u.x; Q[1] += ax * u.y; Q[2] += ax * u.z; Q[3] += ax * u.w;
            Q[4] += ay * u.y; Q[5] += ay * u.z; Q[6] += ay * u.w;
            Q[7] += az * u.z; Q[8] += az * u.w;
            Q[9] += aw * u.w;
        }
    }

#define QUADR(v) { v += __shfl_xor(v, 1); v += __shfl_xor(v, 2); }
    QUADR(T0) QUADR(T1) QUADR(T2)
    QUADR(S0) QUADR(S1) QUADR(S2) QUADR(S3)
#pragma unroll
    for (int i = 0; i < 10; ++i) QUADR(Q[i])
#undef QUADR

    float acc[54];
#pragma unroll
    for (int i = 0; i < 54; ++i) acc[i] = 0.f;

    if (valid && sub == 0) {
        const float inv = 1.0f / npf;
        const float mx = T0 * inv, my = T1 * inv, mz = T2 * inv;
        *reinterpret_cast<float4*>(meta + (size_t)pi * 8) =
            make_float4(mx, my, mz, __int_as_float(np));
        *reinterpret_cast<float4*>(meta + (size_t)pi * 8 + 4) =
            make_float4(cx, cy, 0.f, 0.f);
        const float AS[9] = {S0, S1, S2, S3, S0, S1, S2, S0, S1};
        const float b9[9] = {0.f, 0.f, 0.f, 0.f, -mx, -my, -mz, -cx, -cy};
        const int r9[9] = {0, 1, 2, 3, 0, 1, 2, 0, 1};
        float Qm[4][4];
        Qm[0][0] = Q[0]; Qm[0][1] = Q[1]; Qm[0][2] = Q[2]; Qm[0][3] = Q[3];
        Qm[1][0] = Q[1]; Qm[1][1] = Q[4]; Qm[1][2] = Q[5]; Qm[1][3] = Q[6];
        Qm[2][0] = Q[2]; Qm[2][1] = Q[5]; Qm[2][2] = Q[7]; Qm[2][3] = Q[8];
        Qm[3][0] = Q[3]; Qm[3][1] = Q[6]; Qm[3][2] = Q[8]; Qm[3][3] = Q[9];
#pragma unroll
        for (int i = 0; i < 9; ++i) acc[i] = AS[i] + npf * b9[i];
        int k = 9;
#pragma unroll
        for (int i = 0; i < 9; ++i)
#pragma unroll
            for (int j = i; j < 9; ++j) {
                acc[k] = Qm[r9[i]][r9[j]] + AS[i] * b9[j] + b9[i] * AS[j]
                         + npf * b9[i] * b9[j];
                ++k;
            }
    }

    // reduce across the 16 quad-leader lanes (others hold zeros)
#pragma unroll
    for (int i = 0; i < 54; ++i) {
        acc[i] += __shfl_xor(acc[i], 4);
        acc[i] += __shfl_xor(acc[i], 8);
        acc[i] += __shfl_xor(acc[i], 16);
        acc[i] += __shfl_xor(acc[i], 32);
    }

    __shared__ float red[4][54];
    if (lane == 0) {
#pragma unroll
        for (int i = 0; i < 54; ++i) red[wv][i] = acc[i];
    }
    __syncthreads();
    if (tid < 54) {
        part[(size_t)blockIdx.x * 64 + tid] =
            red[0][tid] + red[1][tid] + red[2][tid] + red[3][tid];
    }
}

// 1 block x 1024 threads: ILP reduce of nb rows + BN fold.
__global__ __launch_bounds__(1024) void k_mid(const float* __restrict__ part,
                                              const float* __restrict__ W,
                                              const float* __restrict__ gamma,
                                              const float* __restrict__ beta,
                                              float* __restrict__ fold,
                                              int nb, int P) {
    __shared__ float sred[16][64];
    __shared__ float ssum[64];
    const int tid = threadIdx.x;
    const int e = tid & 63;
    const int grp = tid >> 6;  // 16 chains per element
    float v0 = 0.f, v1 = 0.f, v2 = 0.f, v3 = 0.f;
    int i = grp;
    for (; i + 48 < nb; i += 64) {
        v0 += part[(size_t)i * 64 + e];
        v1 += part[(size_t)(i + 16) * 64 + e];
        v2 += part[(size_t)(i + 32) * 64 + e];
        v3 += part[(size_t)(i + 48) * 64 + e];
    }
    for (; i < nb; i += 16) v0 += part[(size_t)i * 64 + e];
    sred[grp][e] = (v0 + v1) + (v2 + v3);
    __syncthreads();
    if (tid < 64) {
        float v = 0.f;
#pragma unroll
        for (int g = 0; g < 16; ++g) v += sred[g][tid];
        ssum[tid] = v;  // cols 54..63 junk, never used below
    }
    __syncthreads();

    if (tid < 64) {
        const int d = tid;
        float Wc[9];
#pragma unroll
        for (int c = 0; c < 9; ++c) Wc[c] = W[c * NCH + d];
        const float invPN = 1.0f / ((float)P * (float)NSLOT);
        float mean = 0.f;
#pragma unroll
        for (int c = 0; c < 9; ++c) mean += ssum[c] * Wc[c];
        mean *= invPN;
        float e2 = 0.f;
        int k = 9;
#pragma unroll
        for (int i2 = 0; i2 < 9; ++i2)
#pragma unroll
            for (int j = i2; j < 9; ++j) {
                const float coef = (i2 == j) ? 1.f : 2.f;
                e2 += coef * ssum[k] * Wc[i2] * Wc[j];
                ++k;
            }
        e2 *= invPN;
        const float var = e2 - mean * mean;
        const float s = gamma[d] * rsqrtf(var + kEps);
        const float t = beta[d] - mean * s;
        fold[0 * 64 + d] = s * (Wc[0] + Wc[4] + Wc[7]);  // V0
        fold[1 * 64 + d] = s * (Wc[1] + Wc[5] + Wc[8]);  // V1
        fold[2 * 64 + d] = s * (Wc[2] + Wc[6]);          // V2
        fold[3 * 64 + d] = s * Wc[3];                    // V3
        fold[4 * 64 + d] = s * Wc[4];
        fold[5 * 64 + d] = s * Wc[5];
        fold[6 * 64 + d] = s * Wc[6];
        fold[7 * 64 + d] = s * Wc[7];
        fold[8 * 64 + d] = s * Wc[8];
        fold[9 * 64 + d] = t;
    }
}

__global__ __launch_bounds__(256) void k_out(const float* __restrict__ in,
                                             const float* __restrict__ fold,
                                             const float* __restrict__ meta,
                                             float* __restrict__ out, int P) {
    const int tid = threadIdx.x;
    const int lane = tid & 63;
    const int wv = tid >> 6;
    const int gwave = blockIdx.x * 4 + wv;
    const int nwave = gridDim.x * 4;

    float F[10];
#pragma unroll
    for (int j = 0; j < 10; ++j) F[j] = fold[j * 64 + lane];
    const float V0 = F[0], V1 = F[1], V2 = F[2], V3 = F[3];
    const float sW4 = F[4], sW5 = F[5], sW6 = F[6], sW7 = F[7], sW8 = F[8];
    const float t = F[9];

    for (int p = gwave; p < P; p += nwave) {
        const float* up = uptr(in + (size_t)p * 128);
        const float* mp = uptr(meta + (size_t)p * 8);
        U8 m; U16 g0, g1, g2, g3;
        asm volatile(
            "s_load_dwordx8 %0, %2, 0x0\n\t"
            "s_load_dwordx16 %1, %3, 0x0"
            : "=s"(m.v), "=s"(g0.v) : "s"(mp), "s"(up));
        asm volatile(
            "s_load_dwordx16 %0, %2, 0x40\n\t"
            "s_load_dwordx16 %1, %2, 0x80"
            : "=s"(g1.v), "=s"(g2.v) : "s"(up));
        asm volatile(
            "s_load_dwordx16 %0, %1, 0xc0"
            : "=s"(g3.v) : "s"(up));
        // rule 18: waitcnt in its own asm + sched_barrier so the compiler
        // cannot hoist the SGPR-consuming FMAs above the wait.
        asm volatile("s_waitcnt lgkmcnt(0)" ::: "memory");
        __builtin_amdgcn_sched_barrier(0);

        const int np = m.i[3];  // SGPR -> scalar branches below
        const float c0 = t - fmaf(m.f[0], sW4, fmaf(m.f[1], sW5,
                             fmaf(m.f[2], sW6, fmaf(m.f[4], sW7,
                                  m.f[5] * sW8))));
        // np <= 31 always -> masked slots contribute t; seed with t
        float y0 = t, y1 = t, y2 = t, y3 = t;
#define SLOT4(G, B) { \
        const float z0 = fmaf(G.f[0], V0, fmaf(G.f[1], V1, \
                           fmaf(G.f[2], V2, fmaf(G.f[3], V3, c0)))); \
        const float z1 = fmaf(G.f[4], V0, fmaf(G.f[5], V1, \
                           fmaf(G.f[6], V2, fmaf(G.f[7], V3, c0)))); \
        const float z2 = fmaf(G.f[8], V0, fmaf(G.f[9], V1, \
                           fmaf(G.f[10], V2, fmaf(G.f[11], V3, c0)))); \
        const float z3 = fmaf(G.f[12], V0, fmaf(G.f[13], V1, \
                           fmaf(G.f[14], V2, fmaf(G.f[15], V3, c0)))); \
        y0 = fmaxf(y0, ((B) + 0 < np) ? z0 : t); \
        y1 = fmaxf(y1, ((B) + 1 < np) ? z1 : t); \
        y2 = fmaxf(y2, ((B) + 2 < np) ? z2 : t); \
        y3 = fmaxf(y3, ((B) + 3 < np) ? z3 : t); }

        SLOT4(g0, 0)
        SLOT4(g1, 4)
        if (np > 8) {   // scalar branch (np in SGPR)
            SLOT4(g2, 8)
            SLOT4(g3, 12)
        }
        if (np > 16) {  // scalar branch; ~48% of pillars
            U16 h0, h1, h2, h3;
            asm volatile(
                "s_load_dwordx16 %0, %2, 0x100\n\t"
                "s_load_dwordx16 %1, %2, 0x140"
                : "=s"(h0.v), "=s"(h1.v) : "s"(up));
            asm volatile(
                "s_load_dwordx16 %0, %2, 0x180\n\t"
                "s_load_dwordx16 %1, %2, 0x1c0"
                : "=s"(h2.v), "=s"(h3.v) : "s"(up));
            asm volatile("s_waitcnt lgkmcnt(0)" ::: "memory");
            __builtin_amdgcn_sched_barrier(0);
            SLOT4(h0, 16)
            SLOT4(h1, 20)
            SLOT4(h2, 24)
            SLOT4(h3, 28)
        }
#undef SLOT4
        out[(size_t)p * NCH + lane] =
            fmaxf(fmaxf(fmaxf(y0, y1), fmaxf(y2, y3)), 0.f);
    }
}

extern "C" void kernel_launch(void* const* d_in, const int* in_sizes, int n_in,
                              void* d_out, int out_size, void* d_ws, size_t ws_size,
                              hipStream_t stream) {
    const float* in = (const float*)d_in[0];
    const int* npts = (const int*)d_in[1];
    const int* coords = (const int*)d_in[2];
    const float* W = (const float*)d_in[3];
    const float* gamma = (const float*)d_in[4];
    const float* beta = (const float*)d_in[5];
    float* out = (float*)d_out;
    float* ws = (float*)d_ws;
    const int P = in_sizes[1];  // num_points has P elements

    const int nb = (P + 63) / 64;                 // 469 for P=30000
    const size_t foff = (size_t)nb * 64;          // folded consts offset
    const size_t moff = (foff + 640 + 63) & ~(size_t)63;  // meta offset
    float* part = ws;
    float* fold = ws + foff;
    float* meta = ws + moff;   // ws_size (observed 268 MB) >> 17 MB needed

    k_stats<<<nb, 256, 0, stream>>>(in, npts, coords, part, meta, P);
    k_mid<<<1, 1024, 0, stream>>>(part, W, gamma, beta, fold, nb, P);
    k_out<<<4096, 256, 0, stream>>>(in, fold, meta, out, P);
}